// Round 1
// baseline (11562.283 us; speedup 1.0000x reference)
//
#include <hip/hip_runtime.h>
#include <cstddef>

// ---------------------------------------------------------------------------
// PointNet++ (B=4, N0=4096, NIN=16, NH=128, NOUT=2, DEPTH=3, K=64, R=2, KNN=3)
// fp32 throughout. Selection paths use non-contracted fp32 ops to match the
// numpy/XLA reference's rounding (argmax/top-k index stability).
// ---------------------------------------------------------------------------

#define EPSF 1e-5f

__device__ __forceinline__ float d2_rn(float dx, float dy, float dz) {
    // ((dx*dx + dy*dy) + dz*dz), no fma contraction
    return __fadd_rn(__fadd_rn(__fmul_rn(dx, dx), __fmul_rn(dy, dy)), __fmul_rn(dz, dz));
}

// ---------------- K1: lin_in  xb = relu(x @ W + b), rows=16384 --------------
__global__ __launch_bounds__(128) void lin_in_kernel(
    const float* __restrict__ x, const float* __restrict__ w,
    const float* __restrict__ b, float* __restrict__ xb) {
    __shared__ float sx[16];
    int row = blockIdx.x;
    int t = threadIdx.x;
    if (t < 16) sx[t] = x[row * 16 + t];
    __syncthreads();
    float acc = b[t];
#pragma unroll
    for (int k = 0; k < 16; ++k) acc = fmaf(sx[k], w[k * 128 + t], acc);
    xb[row * 128 + t] = fmaxf(acc, 0.0f);
}

// ---------------- K2: farthest point sampling (1 block per batch) -----------
template <int CHUNK>
__global__ __launch_bounds__(1024) void fps_kernel(
    const float* __restrict__ pts, float* __restrict__ q, int n, int m) {
    __shared__ float px[CHUNK * 1024];
    __shared__ float py[CHUNK * 1024];
    __shared__ float pz[CHUNK * 1024];
    __shared__ float red_v[16];
    __shared__ int   red_i[16];
    __shared__ float lastp[3];
    const int b = blockIdx.x, t = threadIdx.x;
    const float* P = pts + (size_t)b * n * 3;
#pragma unroll
    for (int j = 0; j < CHUNK; ++j) {
        int i = t + j * 1024;
        px[i] = P[i * 3 + 0];
        py[i] = P[i * 3 + 1];
        pz[i] = P[i * 3 + 2];
    }
    if (t == 0) {
        lastp[0] = P[0]; lastp[1] = P[1]; lastp[2] = P[2];
        size_t o = (size_t)b * m * 3;
        q[o] = P[0]; q[o + 1] = P[1]; q[o + 2] = P[2];
    }
    float dmin[CHUNK];
#pragma unroll
    for (int j = 0; j < CHUNK; ++j) dmin[j] = 1e30f;
    __syncthreads();

    for (int step = 1; step < m; ++step) {
        const float lx = lastp[0], ly = lastp[1], lz = lastp[2];
        float bv = -1.0f;
        int bi = 0x7fffffff;
#pragma unroll
        for (int j = 0; j < CHUNK; ++j) {
            int i = t + j * 1024;
            float d = d2_rn(px[i] - lx, py[i] - ly, pz[i] - lz);
            float dm = fminf(dmin[j], d);
            dmin[j] = dm;
            if (dm > bv) { bv = dm; bi = i; }   // strict >: first-index tie-break
        }
#pragma unroll
        for (int off = 32; off >= 1; off >>= 1) {
            float ov = __shfl_down(bv, off, 64);
            int   oi = __shfl_down(bi, off, 64);
            if (ov > bv || (ov == bv && oi < bi)) { bv = ov; bi = oi; }
        }
        if ((t & 63) == 0) { red_v[t >> 6] = bv; red_i[t >> 6] = bi; }
        __syncthreads();
        if (t < 64) {
            float v  = (t < 16) ? red_v[t] : -1.0f;
            int  idx = (t < 16) ? red_i[t] : 0x7fffffff;
#pragma unroll
            for (int off = 8; off >= 1; off >>= 1) {
                float ov = __shfl_down(v, off, 64);
                int   oi = __shfl_down(idx, off, 64);
                if (ov > v || (ov == v && oi < idx)) { v = ov; idx = oi; }
            }
            if (t == 0) {
                float qx = px[idx], qy = py[idx], qz = pz[idx];
                lastp[0] = qx; lastp[1] = qy; lastp[2] = qz;
                size_t o = (size_t)b * m * 3 + (size_t)step * 3;
                q[o] = qx; q[o + 1] = qy; q[o + 2] = qz;
            }
        }
        __syncthreads();
    }
}

// ---------------- K3: radius-ball K=64 nearest selection (1 wave/center) ----
template <int CHUNK, int WAVES>
__global__ void nbr_kernel(const float* __restrict__ pts, const float* __restrict__ q,
                           int* __restrict__ nbr, int n, int m) {
    __shared__ float dst[WAVES * CHUNK * 64];
    const int w = threadIdx.x >> 6, lane = threadIdx.x & 63;
    const int c = blockIdx.x * WAVES + w;
    const int b = c / m;
    float* D = dst + w * CHUNK * 64;
    const float* P = pts + (size_t)b * n * 3;
    const float qx = q[(size_t)c * 3 + 0];
    const float qy = q[(size_t)c * 3 + 1];
    const float qz = q[(size_t)c * 3 + 2];
    for (int s = 0; s < CHUNK; ++s) {
        int i = s * 64 + lane;
        float d2 = d2_rn(P[i * 3] - qx, P[i * 3 + 1] - qy, P[i * 3 + 2] - qz);
        D[i] = (d2 <= 4.0f) ? d2 : 1e30f;   // RADIUS^2 = 4
    }
    int* out = nbr + (size_t)c * 64;
    int cnt = 0;
    for (int round = 0; round < 64; ++round) {
        float bv = 3e38f;
        int bi = 0x7fffffff;
        for (int s = 0; s < CHUNK; ++s) {
            int i = s * 64 + lane;
            float v = D[i];
            if (v < bv) { bv = v; bi = i; }   // strict <: lowest-index tie-break
        }
#pragma unroll
        for (int off = 32; off >= 1; off >>= 1) {
            float ov = __shfl_xor(bv, off, 64);
            int   oi = __shfl_xor(bi, off, 64);
            if (ov < bv || (ov == bv && oi < bi)) { bv = ov; bi = oi; }
        }
        if (bv > 1e29f) break;               // only invalid/removed remain
        if (lane == 0) out[round] = bi;
        if (lane == (bi & 63)) D[bi] = 3e38f;
        ++cnt;
    }
    if (lane >= cnt) out[lane] = -1;
}

// ---------------- K4: fused SA MLP (gather -> 131x131 -> 131x128 -> max) ----
__global__ __launch_bounds__(256) void sa_mlp_kernel(
    const float* __restrict__ xx, const float* __restrict__ pts,
    const float* __restrict__ q, const int* __restrict__ nbr,
    const float* __restrict__ w1, const float* __restrict__ b1,
    const float* __restrict__ g1, const float* __restrict__ be1,
    const float* __restrict__ w2, const float* __restrict__ b2,
    const float* __restrict__ g2, const float* __restrict__ be2,
    float* __restrict__ hout, int n, int m) {
    __shared__ __align__(16) float sh_hin[32][132];
    __shared__ __align__(16) float sh_o1[32][132];
    __shared__ __align__(16) float sh_w[32][132];
    __shared__ int   sh_nbr[64];
    __shared__ float sh_q[3];
    __shared__ float sh_max[128];
    __shared__ int   sh_cnt;

    const int t = threadIdx.x;
    const int c = blockIdx.x;
    const int b = c / m;
    const float invs = 1.0f / sqrtf(1.0f + EPSF);

    if (t < 64) sh_nbr[t] = nbr[(size_t)c * 64 + t];
    if (t < 3) sh_q[t] = q[(size_t)c * 3 + t];
    if (t < 128) sh_max[t] = -1e30f;
    __syncthreads();
    if (t == 0) {
        int cc = 0;
        while (cc < 64 && sh_nbr[cc] >= 0) ++cc;
        sh_cnt = cc;
    }
    __syncthreads();
    const int cnt = sh_cnt;

    const int rt1 = t >> 5, ct1 = t & 31;  // 8 row-tiles x 32 col-tiles (4x4)
    const int xr = t / 3, xcol = t - xr * 3;  // extra cols 128..130 (t < 96)

    for (int half = 0; half < 2; ++half) {
        const int r0 = half * 32;
        int rc = cnt - r0;
        if (rc > 32) rc = 32;
        if (rc <= 0) break;
        const int rtu = (rc + 3) >> 2;

        // ---- stage gathered input rows: [xx | p - q] (131 each) ----
        for (int rr = 0; rr < rc; ++rr) {
            int g = sh_nbr[r0 + rr];
            if (t < 131) {
                float v;
                if (t < 128) v = xx[((size_t)b * n + g) * 128 + t];
                else         v = pts[((size_t)b * n + g) * 3 + (t - 128)] - sh_q[t - 128];
                sh_hin[rr][t] = v;
            }
        }
        __syncthreads();

        // ---- layer 1: 131 -> 131 ----
        float acc[16];
#pragma unroll
        for (int i = 0; i < 16; ++i) acc[i] = 0.0f;
        float accx = 0.0f;
        for (int k0 = 0; k0 < 131; k0 += 32) {
            int kc = 131 - k0; if (kc > 32) kc = 32;
            for (int kk = 0; kk < kc; ++kk)
                if (t < 131) sh_w[kk][t] = w1[(k0 + kk) * 131 + t];
            __syncthreads();
            if (rt1 < rtu) {
                for (int kk = 0; kk < kc; ++kk) {
                    float av[4];
#pragma unroll
                    for (int i = 0; i < 4; ++i) av[i] = sh_hin[4 * rt1 + i][k0 + kk];
                    const float4 wv = *(const float4*)&sh_w[kk][4 * ct1];
                    const float wa[4] = {wv.x, wv.y, wv.z, wv.w};
#pragma unroll
                    for (int i = 0; i < 4; ++i)
#pragma unroll
                        for (int jj = 0; jj < 4; ++jj)
                            acc[i * 4 + jj] = fmaf(av[i], wa[jj], acc[i * 4 + jj]);
                }
            }
            if (t < 96 && xr < rc) {
                for (int kk = 0; kk < kc; ++kk)
                    accx = fmaf(sh_hin[xr][k0 + kk], sh_w[kk][128 + xcol], accx);
            }
            __syncthreads();
        }
        if (rt1 < rtu) {
#pragma unroll
            for (int i = 0; i < 4; ++i)
#pragma unroll
                for (int jj = 0; jj < 4; ++jj) {
                    int col = 4 * ct1 + jj;
                    float z = fmaxf(acc[i * 4 + jj] + b1[col], 0.0f);
                    sh_o1[4 * rt1 + i][col] = g1[col] * z * invs + be1[col];
                }
        }
        if (t < 96 && xr < rc) {
            int col = 128 + xcol;
            float z = fmaxf(accx + b1[col], 0.0f);
            sh_o1[xr][col] = g1[col] * z * invs + be1[col];
        }
        __syncthreads();

        // ---- layer 2: 131 -> 128 ----
        float acc2[16];
#pragma unroll
        for (int i = 0; i < 16; ++i) acc2[i] = 0.0f;
        for (int k0 = 0; k0 < 131; k0 += 32) {
            int kc = 131 - k0; if (kc > 32) kc = 32;
            for (int kk = 0; kk < kc; ++kk)
                if (t < 128) sh_w[kk][t] = w2[(k0 + kk) * 128 + t];
            __syncthreads();
            if (rt1 < rtu) {
                for (int kk = 0; kk < kc; ++kk) {
                    float av[4];
#pragma unroll
                    for (int i = 0; i < 4; ++i) av[i] = sh_o1[4 * rt1 + i][k0 + kk];
                    const float4 wv = *(const float4*)&sh_w[kk][4 * ct1];
                    const float wa[4] = {wv.x, wv.y, wv.z, wv.w};
#pragma unroll
                    for (int i = 0; i < 4; ++i)
#pragma unroll
                        for (int jj = 0; jj < 4; ++jj)
                            acc2[i * 4 + jj] = fmaf(av[i], wa[jj], acc2[i * 4 + jj]);
                }
            }
            __syncthreads();
        }
        // epilogue + per-tile masked max (invalid rows skipped == ref's -1e30 mask)
        if (rt1 < rtu) {
#pragma unroll
            for (int jj = 0; jj < 4; ++jj) {
                int col = 4 * ct1 + jj;
                float mx = -1e30f;
#pragma unroll
                for (int i = 0; i < 4; ++i) {
                    if (4 * rt1 + i < rc) {
                        float z = fmaxf(acc2[i * 4 + jj] + b2[col], 0.0f);
                        float v = g2[col] * z * invs + be2[col];
                        mx = fmaxf(mx, v);
                    }
                }
                sh_hin[rt1][col] = mx;  // reuse sh_hin as [8][132] reduce buffer
            }
        }
        __syncthreads();
        if (t < 128) {
            float mx = sh_max[t];
            for (int rt = 0; rt < rtu; ++rt) mx = fmaxf(mx, sh_hin[rt][t]);
            sh_max[t] = mx;
        }
        __syncthreads();
    }
    if (t < 128) hout[(size_t)c * 128 + t] = sh_max[t];
}

// ---------------- K5a: 3-NN search + inverse-d2 weights --------------------
__global__ __launch_bounds__(256) void knn_kernel(
    const float* __restrict__ pf, const float* __restrict__ pc,
    int* __restrict__ kidx, float* __restrict__ kw, int nf, int nc) {
    const int tg = blockIdx.x * 256 + threadIdx.x;  // 0..B*nf-1 (exact grid)
    const int b = tg / nf;
    const float* F = pf + (size_t)tg * 3;
    const float fx = F[0], fy = F[1], fz = F[2];
    const float* C = pc + (size_t)b * nc * 3;
    float b0 = 1e30f, b1 = 1e30f, b2 = 1e30f;
    int i0 = 0, i1 = 0, i2 = 0;
    for (int j = 0; j < nc; ++j) {
        float d2 = d2_rn(C[j * 3] - fx, C[j * 3 + 1] - fy, C[j * 3 + 2] - fz);
        if (d2 < b0)      { b2 = b1; i2 = i1; b1 = b0; i1 = i0; b0 = d2; i0 = j; }
        else if (d2 < b1) { b2 = b1; i2 = i1; b1 = d2; i1 = j; }
        else if (d2 < b2) { b2 = d2; i2 = j; }
    }
    float w0 = 1.0f / fmaxf(b0, 1e-16f);
    float w1 = 1.0f / fmaxf(b1, 1e-16f);
    float w2 = 1.0f / fmaxf(b2, 1e-16f);
    float inv = 1.0f / (w0 + w1 + w2);
    size_t o = (size_t)tg * 3;
    kidx[o] = i0; kidx[o + 1] = i1; kidx[o + 2] = i2;
    kw[o] = w0 * inv; kw[o + 1] = w1 * inv; kw[o + 2] = w2 * inv;
}

// ---------------- K5b: interpolate + concat skip -> cat[f][256] -------------
__global__ __launch_bounds__(256) void interp_cat_kernel(
    const float* __restrict__ xc, const float* __restrict__ xs,
    const int* __restrict__ kidx, const float* __restrict__ kw,
    float* __restrict__ cat, int nf, int nc) {
    const int f = blockIdx.x;   // 0..B*nf-1
    const int t = threadIdx.x;
    const int b = f / nf;
    const size_t o = (size_t)f * 3;
    if (t < 128) {
        int i0 = kidx[o], i1 = kidx[o + 1], i2 = kidx[o + 2];
        float w0 = kw[o], w1 = kw[o + 1], w2 = kw[o + 2];
        const float* X = xc + (size_t)b * nc * 128;
        float y = w0 * X[(size_t)i0 * 128 + t] + w1 * X[(size_t)i1 * 128 + t] +
                  w2 * X[(size_t)i2 * 128 + t];
        cat[(size_t)f * 256 + t] = y;
    } else {
        cat[(size_t)f * 256 + t] = xs[(size_t)f * 128 + (t - 128)];
    }
}

// ---------------- K6: generic GEMM + bias + relu + BN epilogue --------------
// C[R,Cout] = bn(relu(A[R,Kin] @ W[Kin,Cout] + bias)); R%64==0, Kin%32==0, Cout%64==0
__global__ __launch_bounds__(256) void gemm_bn_kernel(
    const float* __restrict__ A, const float* __restrict__ W,
    const float* __restrict__ bias, const float* __restrict__ g,
    const float* __restrict__ be, float* __restrict__ C, int Kin, int Cout) {
    __shared__ __align__(16) float shA[64][33];
    __shared__ __align__(16) float shB[32][68];
    const int t = threadIdx.x;
    const int r0 = blockIdx.x * 64;
    const int c0 = blockIdx.y * 64;
    const int tr = t >> 4, tc = t & 15;
    const float invs = 1.0f / sqrtf(1.0f + EPSF);
    float acc[16];
#pragma unroll
    for (int i = 0; i < 16; ++i) acc[i] = 0.0f;
    for (int k0 = 0; k0 < Kin; k0 += 32) {
#pragma unroll
        for (int e = t; e < 2048; e += 256) {
            int r = e >> 5, kk = e & 31;
            shA[r][kk] = A[(size_t)(r0 + r) * Kin + k0 + kk];
        }
#pragma unroll
        for (int e = t; e < 2048; e += 256) {
            int kk = e >> 6, cc = e & 63;
            shB[kk][cc] = W[(size_t)(k0 + kk) * Cout + c0 + cc];
        }
        __syncthreads();
        for (int kk = 0; kk < 32; ++kk) {
            float av[4];
#pragma unroll
            for (int i = 0; i < 4; ++i) av[i] = shA[4 * tr + i][kk];
            const float4 wv = *(const float4*)&shB[kk][4 * tc];
            const float wa[4] = {wv.x, wv.y, wv.z, wv.w};
#pragma unroll
            for (int i = 0; i < 4; ++i)
#pragma unroll
                for (int jj = 0; jj < 4; ++jj)
                    acc[i * 4 + jj] = fmaf(av[i], wa[jj], acc[i * 4 + jj]);
        }
        __syncthreads();
    }
#pragma unroll
    for (int i = 0; i < 4; ++i)
#pragma unroll
        for (int jj = 0; jj < 4; ++jj) {
            int col = c0 + 4 * tc + jj;
            float z = fmaxf(acc[i * 4 + jj] + bias[col], 0.0f);
            C[(size_t)(r0 + 4 * tr + i) * Cout + col] = g[col] * z * invs + be[col];
        }
}

// ---------------- K7: final 128 -> 2 layer ----------------------------------
__global__ __launch_bounds__(256) void lo2_kernel(
    const float* __restrict__ in, const float* __restrict__ w,
    const float* __restrict__ b, const float* __restrict__ g,
    const float* __restrict__ be, float* __restrict__ out) {
    __shared__ float sw[256];
    const int t = threadIdx.x;
    sw[t] = w[t];
    __syncthreads();
    const int row = blockIdx.x * 256 + t;
    const float invs = 1.0f / sqrtf(1.0f + EPSF);
    float a0 = b[0], a1 = b[1];
    const float* R = in + (size_t)row * 128;
    for (int k = 0; k < 128; ++k) {
        float a = R[k];
        a0 = fmaf(a, sw[k * 2], a0);
        a1 = fmaf(a, sw[k * 2 + 1], a1);
    }
    a0 = fmaxf(a0, 0.0f);
    a1 = fmaxf(a1, 0.0f);
    out[(size_t)row * 2]     = g[0] * a0 * invs + be[0];
    out[(size_t)row * 2 + 1] = g[1] * a1 * invs + be[1];
}

// ---------------------------------------------------------------------------
extern "C" void kernel_launch(void* const* d_in, const int* in_sizes, int n_in,
                              void* d_out, int out_size, void* d_ws, size_t ws_size,
                              hipStream_t stream) {
    const float* x      = (const float*)d_in[0];
    const float* pos    = (const float*)d_in[1];
    const float* lin_w  = (const float*)d_in[3];
    const float* lin_b  = (const float*)d_in[4];
    const float* sa_w1  = (const float*)d_in[5];
    const float* sa_b1  = (const float*)d_in[6];
    const float* sa_g1  = (const float*)d_in[7];
    const float* sa_be1 = (const float*)d_in[8];
    const float* sa_w2  = (const float*)d_in[9];
    const float* sa_b2  = (const float*)d_in[10];
    const float* sa_g2  = (const float*)d_in[11];
    const float* sa_be2 = (const float*)d_in[12];
    const float* fp_w1  = (const float*)d_in[13];
    const float* fp_b1  = (const float*)d_in[14];
    const float* fp_g1  = (const float*)d_in[15];
    const float* fp_be1 = (const float*)d_in[16];
    const float* fp_w2  = (const float*)d_in[17];
    const float* fp_b2  = (const float*)d_in[18];
    const float* fp_g2  = (const float*)d_in[19];
    const float* fp_be2 = (const float*)d_in[20];
    const float* lo_w1  = (const float*)d_in[21];
    const float* lo_b1  = (const float*)d_in[22];
    const float* lo_g1  = (const float*)d_in[23];
    const float* lo_be1 = (const float*)d_in[24];
    const float* lo_w2  = (const float*)d_in[25];
    const float* lo_b2  = (const float*)d_in[26];
    const float* lo_g2  = (const float*)d_in[27];
    const float* lo_be2 = (const float*)d_in[28];

    float* ws = (float*)d_ws;
    size_t off = 0;
    auto alloc = [&](size_t n) { float* p = ws + off; off += n; return p; };
    float* xb   = alloc(4 * 4096 * 128);
    float* q1   = alloc(4 * 2048 * 3);
    float* q2   = alloc(4 * 1024 * 3);
    float* q3   = alloc(4 * 512 * 3);
    float* h1   = alloc(4 * 2048 * 128);
    float* h2   = alloc(4 * 1024 * 128);
    float* h3   = alloc(4 * 512 * 128);
    int* nbr1   = (int*)alloc(4 * 2048 * 64);
    int* nbr2   = (int*)alloc(4 * 1024 * 64);
    int* nbr3   = (int*)alloc(4 * 512 * 64);
    int* kidx   = (int*)alloc(4 * 4096 * 3);
    float* kw   = alloc(4 * 4096 * 3);
    float* cat  = alloc(4 * 4096 * 256);
    float* mbuf = alloc(4 * 4096 * 256);
    float* xfA  = alloc(4 * 4096 * 128);
    float* xfB  = alloc(4 * 4096 * 128);
    if (ws_size < off * sizeof(float)) return;  // workspace too small: fail loudly

    // lin_in
    lin_in_kernel<<<16384, 128, 0, stream>>>(x, lin_w, lin_b, xb);

    // ---- SA level 0: 4096 -> 2048 ----
    fps_kernel<4><<<4, 1024, 0, stream>>>(pos, q1, 4096, 2048);
    nbr_kernel<64, 2><<<4096, 128, 0, stream>>>(pos, q1, nbr1, 4096, 2048);
    sa_mlp_kernel<<<8192, 256, 0, stream>>>(xb, pos, q1, nbr1,
        sa_w1, sa_b1, sa_g1, sa_be1, sa_w2, sa_b2, sa_g2, sa_be2,
        h1, 4096, 2048);

    // ---- SA level 1: 2048 -> 1024 ----
    fps_kernel<2><<<4, 1024, 0, stream>>>(q1, q2, 2048, 1024);
    nbr_kernel<32, 4><<<1024, 256, 0, stream>>>(q1, q2, nbr2, 2048, 1024);
    sa_mlp_kernel<<<4096, 256, 0, stream>>>(h1, q1, q2, nbr2,
        sa_w1 + 131 * 131, sa_b1 + 131, sa_g1 + 131, sa_be1 + 131,
        sa_w2 + 131 * 128, sa_b2 + 128, sa_g2 + 128, sa_be2 + 128,
        h2, 2048, 1024);

    // ---- SA level 2: 1024 -> 512 ----
    fps_kernel<1><<<4, 1024, 0, stream>>>(q2, q3, 1024, 512);
    nbr_kernel<16, 4><<<512, 256, 0, stream>>>(q2, q3, nbr3, 1024, 512);
    sa_mlp_kernel<<<2048, 256, 0, stream>>>(h2, q2, q3, nbr3,
        sa_w1 + 2 * 131 * 131, sa_b1 + 2 * 131, sa_g1 + 2 * 131, sa_be1 + 2 * 131,
        sa_w2 + 2 * 131 * 128, sa_b2 + 2 * 128, sa_g2 + 2 * 128, sa_be2 + 2 * 128,
        h3, 1024, 512);

    // ---- FP step 0 (mi=2): coarse (h3 @ q3, 512) -> fine q2 (1024), skip h2 ----
    knn_kernel<<<(4 * 1024) / 256, 256, 0, stream>>>(q2, q3, kidx, kw, 1024, 512);
    interp_cat_kernel<<<4 * 1024, 256, 0, stream>>>(h3, h2, kidx, kw, cat, 1024, 512);
    gemm_bn_kernel<<<dim3(4096 / 64, 4), 256, 0, stream>>>(cat,
        fp_w1 + 2 * 256 * 256, fp_b1 + 2 * 256, fp_g1 + 2 * 256, fp_be1 + 2 * 256,
        mbuf, 256, 256);
    gemm_bn_kernel<<<dim3(4096 / 64, 2), 256, 0, stream>>>(mbuf,
        fp_w2 + 2 * 256 * 128, fp_b2 + 2 * 128, fp_g2 + 2 * 128, fp_be2 + 2 * 128,
        xfA, 256, 128);

    // ---- FP step 1 (mi=1): coarse (xfA @ q2, 1024) -> fine q1 (2048), skip h1 ----
    knn_kernel<<<(4 * 2048) / 256, 256, 0, stream>>>(q1, q2, kidx, kw, 2048, 1024);
    interp_cat_kernel<<<4 * 2048, 256, 0, stream>>>(xfA, h1, kidx, kw, cat, 2048, 1024);
    gemm_bn_kernel<<<dim3(8192 / 64, 4), 256, 0, stream>>>(cat,
        fp_w1 + 256 * 256, fp_b1 + 256, fp_g1 + 256, fp_be1 + 256,
        mbuf, 256, 256);
    gemm_bn_kernel<<<dim3(8192 / 64, 2), 256, 0, stream>>>(mbuf,
        fp_w2 + 256 * 128, fp_b2 + 128, fp_g2 + 128, fp_be2 + 128,
        xfB, 256, 128);

    // ---- FP step 2 (mi=0): coarse (xfB @ q1, 2048) -> fine pos (4096), skip xb ----
    knn_kernel<<<(4 * 4096) / 256, 256, 0, stream>>>(pos, q1, kidx, kw, 4096, 2048);
    interp_cat_kernel<<<4 * 4096, 256, 0, stream>>>(xfB, xb, kidx, kw, cat, 4096, 2048);
    gemm_bn_kernel<<<dim3(16384 / 64, 4), 256, 0, stream>>>(cat,
        fp_w1, fp_b1, fp_g1, fp_be1, mbuf, 256, 256);
    gemm_bn_kernel<<<dim3(16384 / 64, 2), 256, 0, stream>>>(mbuf,
        fp_w2, fp_b2, fp_g2, fp_be2, xfA, 256, 128);

    // ---- output MLP ----
    gemm_bn_kernel<<<dim3(16384 / 64, 2), 256, 0, stream>>>(xfA,
        lo_w1, lo_b1, lo_g1, lo_be1, mbuf, 128, 128);
    lo2_kernel<<<16384 / 256, 256, 0, stream>>>(mbuf, lo_w2, lo_b2, lo_g2, lo_be2,
        (float*)d_out);
}

// Round 2
// 6362.919 us; speedup vs baseline: 1.8171x; 1.8171x over previous
//
#include <hip/hip_runtime.h>
#include <cstddef>

// ---------------------------------------------------------------------------
// PointNet++ (B=4, N0=4096, NIN=16, NH=128, NOUT=2, DEPTH=3, K=64, R=2, KNN=3)
// fp32. Selection paths (FPS argmax, radius top-K, 3-NN) use non-contracted
// fp32 ops + first-index tie-breaks to match the reference bit-for-bit.
// SA MLP = compacted batched GEMM over valid (center,point) pairs with
// atomicMax (uint bits, values >= 0) scatter for the max-aggregation.
// ---------------------------------------------------------------------------

#define EPSF 1e-5f

__device__ __forceinline__ float d2_rn(float dx, float dy, float dz) {
    return __fadd_rn(__fadd_rn(__fmul_rn(dx, dx), __fmul_rn(dy, dy)), __fmul_rn(dz, dz));
}

// ---------------- K1: lin_in  xb = relu(x @ W + b), rows=16384 --------------
__global__ __launch_bounds__(128) void lin_in_kernel(
    const float* __restrict__ x, const float* __restrict__ w,
    const float* __restrict__ b, float* __restrict__ xb) {
    __shared__ float sx[16];
    int row = blockIdx.x;
    int t = threadIdx.x;
    if (t < 16) sx[t] = x[row * 16 + t];
    __syncthreads();
    float acc = b[t];
#pragma unroll
    for (int k = 0; k < 16; ++k) acc = fmaf(sx[k], w[k * 128 + t], acc);
    xb[row * 128 + t] = fmaxf(acc, 0.0f);
}

// ---------------- K2: FPS, register-resident, 1 barrier/step ---------------
template <int N, int NT>
__global__ __launch_bounds__(NT) void fps_kernel(
    const float* __restrict__ pts, float* __restrict__ q, int m) {
    constexpr int PPT = N / NT;
    constexpr int NW = NT / 64;
    __shared__ float s_px[N], s_py[N], s_pz[N];
    __shared__ float s_bv[2][NW];
    __shared__ int   s_bi[2][NW];
    const int b = blockIdx.x, t = threadIdx.x;
    const float* P = pts + (size_t)b * N * 3;
    float rx[PPT], ry[PPT], rz[PPT], dmin[PPT];
#pragma unroll
    for (int j = 0; j < PPT; ++j) {
        int i = j * NT + t;
        float x = P[i * 3], y = P[i * 3 + 1], z = P[i * 3 + 2];
        rx[j] = x; ry[j] = y; rz[j] = z; dmin[j] = 1e30f;
        s_px[i] = x; s_py[i] = y; s_pz[i] = z;
    }
    float lx = P[0], ly = P[1], lz = P[2];
    if (t == 0) { size_t o = (size_t)b * m * 3; q[o] = lx; q[o + 1] = ly; q[o + 2] = lz; }
    __syncthreads();
    for (int step = 1; step < m; ++step) {
        float bv = -1.0f; int bi = 0x7fffffff;
#pragma unroll
        for (int j = 0; j < PPT; ++j) {
            float d = d2_rn(rx[j] - lx, ry[j] - ly, rz[j] - lz);
            float dm = fminf(dmin[j], d);
            dmin[j] = dm;
            if (dm > bv) { bv = dm; bi = j * NT + t; }  // strict >: lowest idx in-thread
        }
#pragma unroll
        for (int off = 32; off >= 1; off >>= 1) {
            float ov = __shfl_xor(bv, off, 64);
            int   oi = __shfl_xor(bi, off, 64);
            if (ov > bv || (ov == bv && oi < bi)) { bv = ov; bi = oi; }
        }
        const int p = step & 1;
        if ((t & 63) == 0) { s_bv[p][t >> 6] = bv; s_bi[p][t >> 6] = bi; }
        __syncthreads();
        bv = s_bv[p][0]; bi = s_bi[p][0];
#pragma unroll
        for (int w = 1; w < NW; ++w) {
            float ov = s_bv[p][w]; int oi = s_bi[p][w];
            if (ov > bv || (ov == bv && oi < bi)) { bv = ov; bi = oi; }
        }
        lx = s_px[bi]; ly = s_py[bi]; lz = s_pz[bi];
        if (t == 0) {
            size_t o = (size_t)b * m * 3 + (size_t)step * 3;
            q[o] = lx; q[o + 1] = ly; q[o + 2] = lz;
        }
        // double-buffered s_bv/s_bi: next step's leader writes go to buffer p^1,
        // so one barrier per step suffices.
    }
}

// ---------------- K3: zero hout + pair counter ------------------------------
__global__ void zero_kernel(float* __restrict__ buf, int n, unsigned* __restrict__ counter) {
    int i = blockIdx.x * 256 + threadIdx.x;
    if (i < n) buf[i] = 0.0f;
    if (i == 0) *counter = 0u;
}

// ---------------- K4: radius-ball K=64 selection -> compacted pair list -----
template <int CHUNK, int WAVES>
__global__ void nbr_kernel(const float* __restrict__ pts, const float* __restrict__ q,
                           int2* __restrict__ pairs, unsigned* __restrict__ counter,
                           int n, int m) {
    __shared__ float dst[WAVES * CHUNK * 64];
    const int w = threadIdx.x >> 6, lane = threadIdx.x & 63;
    const int c = blockIdx.x * WAVES + w;
    const int b = c / m;
    float* D = dst + w * CHUNK * 64;
    const float* P = pts + (size_t)b * n * 3;
    const float qx = q[(size_t)c * 3 + 0];
    const float qy = q[(size_t)c * 3 + 1];
    const float qz = q[(size_t)c * 3 + 2];
    for (int s = 0; s < CHUNK; ++s) {
        int i = s * 64 + lane;
        float d2 = d2_rn(P[i * 3] - qx, P[i * 3 + 1] - qy, P[i * 3 + 2] - qz);
        D[i] = (d2 <= 4.0f) ? d2 : 1e30f;   // RADIUS^2 = 4
    }
    int my_g = -1;
    int cnt = 0;
    for (int round = 0; round < 64; ++round) {
        float bv = 3e38f;
        int bi = 0x7fffffff;
        for (int s = 0; s < CHUNK; ++s) {
            int i = s * 64 + lane;
            float v = D[i];
            if (v < bv) { bv = v; bi = i; }   // strict <: lowest-index tie-break
        }
#pragma unroll
        for (int off = 32; off >= 1; off >>= 1) {
            float ov = __shfl_xor(bv, off, 64);
            int   oi = __shfl_xor(bi, off, 64);
            if (ov < bv || (ov == bv && oi < bi)) { bv = ov; bi = oi; }
        }
        if (bv > 1e29f) break;               // only invalid/removed remain (uniform)
        if (round == lane) my_g = bi;
        if (lane == (bi & 63)) D[bi] = 3e38f;
        ++cnt;
    }
    unsigned base = 0;
    if (lane == 0) base = atomicAdd(counter, (unsigned)cnt);
    base = (unsigned)__shfl((int)base, 0, 64);
    if (lane < cnt) pairs[base + lane] = make_int2(c, my_g);
}

// ---------------- K5: fused SA MLP over compacted rows ----------------------
// 64 rows/block: gather [xx | p-q] -> 131x131 -> 131x128 -> segmented max ->
// atomicMax scatter. K padded to 132 with zero row/cols.
__global__ __launch_bounds__(256) void sa_fused_kernel(
    const float* __restrict__ xx, const float* __restrict__ pts,
    const float* __restrict__ q, const int2* __restrict__ pairs,
    const unsigned* __restrict__ vcount,
    const float* __restrict__ w1, const float* __restrict__ b1,
    const float* __restrict__ g1, const float* __restrict__ be1,
    const float* __restrict__ w2, const float* __restrict__ b2,
    const float* __restrict__ g2, const float* __restrict__ be2,
    float* __restrict__ hout, int lm, int ln) {
    __shared__ __align__(16) float shA[64][132];   // gather -> H1 -> out (reused)
    __shared__ __align__(16) float shW[32][132];
    __shared__ int sh_c[64], sh_g[64];
    const int t = threadIdx.x;
    const int V = (int)*vcount;
    const int r0 = blockIdx.x * 64;
    if (r0 >= V) return;
    if (t < 64) {
        int r = r0 + t;
        if (r < V) { int2 p = pairs[r]; sh_c[t] = p.x; sh_g[t] = p.y; }
        else { sh_c[t] = -1; sh_g[t] = 0; }
    }
    __syncthreads();

    // ---- gather A: 64 rows x 132 cols (33 float4 chunks per row) ----
    for (int e = t; e < 64 * 33; e += 256) {
        int row = e / 33, cid = e - row * 33;
        int c = sh_c[row];
        float4 v = make_float4(0.f, 0.f, 0.f, 0.f);
        if (c >= 0) {
            int g = sh_g[row];
            int b = c >> lm;
            size_t pt = ((size_t)(b << ln) + g);
            if (cid < 32) {
                v = *(const float4*)(xx + (pt << 7) + cid * 4);
            } else {
                const float* P = pts + pt * 3;
                const float* Q = q + (size_t)c * 3;
                v.x = P[0] - Q[0]; v.y = P[1] - Q[1]; v.z = P[2] - Q[2]; v.w = 0.f;
            }
        }
        *(float4*)&shA[row][cid * 4] = v;
    }
    __syncthreads();

    const float invs = 1.0f / sqrtf(1.0f + EPSF);
    const int tr = t >> 4, tc = t & 15;       // rows 4tr..4tr+3, cols 8tc..8tc+7
    const int xrow = t >> 2, xcol = t & 3;    // extra cols 128..131
    float acc[32];
#pragma unroll
    for (int i = 0; i < 32; ++i) acc[i] = 0.0f;
    float accx = 0.0f;

    // ---- layer 1: K=132 (rows/cols >=131 zero-padded) ----
    for (int k0 = 0; k0 < 132; k0 += 32) {
        const int kc = (132 - k0 < 32) ? (132 - k0) : 32;
        for (int e = t; e < kc * 132; e += 256) {
            int kk = e / 132, j = e - kk * 132;
            int k = k0 + kk;
            shW[kk][j] = (k < 131 && j < 131) ? w1[k * 131 + j] : 0.0f;
        }
        __syncthreads();
        for (int kk = 0; kk < kc; ++kk) {
            const int k = k0 + kk;
            float a0 = shA[4 * tr + 0][k], a1 = shA[4 * tr + 1][k];
            float a2 = shA[4 * tr + 2][k], a3 = shA[4 * tr + 3][k];
            const float4 w0 = *(const float4*)&shW[kk][8 * tc];
            const float4 w1v = *(const float4*)&shW[kk][8 * tc + 4];
            const float wa[8] = {w0.x, w0.y, w0.z, w0.w, w1v.x, w1v.y, w1v.z, w1v.w};
#pragma unroll
            for (int j = 0; j < 8; ++j) {
                acc[0 * 8 + j] = fmaf(a0, wa[j], acc[0 * 8 + j]);
                acc[1 * 8 + j] = fmaf(a1, wa[j], acc[1 * 8 + j]);
                acc[2 * 8 + j] = fmaf(a2, wa[j], acc[2 * 8 + j]);
                acc[3 * 8 + j] = fmaf(a3, wa[j], acc[3 * 8 + j]);
            }
            accx = fmaf(shA[xrow][k], shW[kk][128 + xcol], accx);
        }
        __syncthreads();
    }
    // epilogue 1 -> H1 into shA
#pragma unroll
    for (int i = 0; i < 4; ++i)
#pragma unroll
        for (int j = 0; j < 8; ++j) {
            int col = 8 * tc + j;
            float z = fmaxf(acc[i * 8 + j] + b1[col], 0.0f);
            shA[4 * tr + i][col] = g1[col] * z * invs + be1[col];
        }
    if (xcol < 3) {
        int col = 128 + xcol;
        float z = fmaxf(accx + b1[col], 0.0f);
        shA[xrow][col] = g1[col] * z * invs + be1[col];
    } else {
        shA[xrow][131] = 0.0f;   // zero K-pad col (w2 row 131 is also zeroed)
    }

    // ---- layer 2: 132 -> 128 ----
#pragma unroll
    for (int i = 0; i < 32; ++i) acc[i] = 0.0f;
    for (int k0 = 0; k0 < 132; k0 += 32) {
        const int kc = (132 - k0 < 32) ? (132 - k0) : 32;
        for (int e = t; e < kc * 132; e += 256) {
            int kk = e / 132, j = e - kk * 132;
            int k = k0 + kk;
            shW[kk][j] = (k < 131 && j < 128) ? w2[k * 128 + j] : 0.0f;
        }
        __syncthreads();
        for (int kk = 0; kk < kc; ++kk) {
            const int k = k0 + kk;
            float a0 = shA[4 * tr + 0][k], a1 = shA[4 * tr + 1][k];
            float a2 = shA[4 * tr + 2][k], a3 = shA[4 * tr + 3][k];
            const float4 w0 = *(const float4*)&shW[kk][8 * tc];
            const float4 w1v = *(const float4*)&shW[kk][8 * tc + 4];
            const float wa[8] = {w0.x, w0.y, w0.z, w0.w, w1v.x, w1v.y, w1v.z, w1v.w};
#pragma unroll
            for (int j = 0; j < 8; ++j) {
                acc[0 * 8 + j] = fmaf(a0, wa[j], acc[0 * 8 + j]);
                acc[1 * 8 + j] = fmaf(a1, wa[j], acc[1 * 8 + j]);
                acc[2 * 8 + j] = fmaf(a2, wa[j], acc[2 * 8 + j]);
                acc[3 * 8 + j] = fmaf(a3, wa[j], acc[3 * 8 + j]);
            }
        }
        __syncthreads();
    }
    // epilogue 2 -> out into shA (cols 0..127)
#pragma unroll
    for (int i = 0; i < 4; ++i)
#pragma unroll
        for (int j = 0; j < 8; ++j) {
            int col = 8 * tc + j;
            float z = fmaxf(acc[i * 8 + j] + b2[col], 0.0f);
            shA[4 * tr + i][col] = g2[col] * z * invs + be2[col];
        }
    __syncthreads();

    // ---- segmented max over contiguous same-center rows + atomic scatter ----
    if (t < 128) {
        const int col = t;
        float run = -1.0f;
        int cur = sh_c[0];
        for (int row = 0; row < 64; ++row) {
            int c = sh_c[row];
            if (c != cur) {
                if (cur >= 0)
                    atomicMax((unsigned*)&hout[((size_t)cur << 7) + col], __float_as_uint(run));
                run = -1.0f; cur = c;
            }
            run = fmaxf(run, shA[row][col]);
        }
        if (cur >= 0)
            atomicMax((unsigned*)&hout[((size_t)cur << 7) + col], __float_as_uint(run));
    }
}

// ---------------- K6a: 3-NN search + inverse-d2 weights --------------------
__global__ __launch_bounds__(256) void knn_kernel(
    const float* __restrict__ pf, const float* __restrict__ pc,
    int* __restrict__ kidx, float* __restrict__ kw, int nf, int nc) {
    const int tg = blockIdx.x * 256 + threadIdx.x;
    const int b = tg / nf;
    const float* F = pf + (size_t)tg * 3;
    const float fx = F[0], fy = F[1], fz = F[2];
    const float* C = pc + (size_t)b * nc * 3;
    float b0 = 1e30f, b1 = 1e30f, b2 = 1e30f;
    int i0 = 0, i1 = 0, i2 = 0;
    for (int j = 0; j < nc; ++j) {
        float d2 = d2_rn(C[j * 3] - fx, C[j * 3 + 1] - fy, C[j * 3 + 2] - fz);
        if (d2 < b0)      { b2 = b1; i2 = i1; b1 = b0; i1 = i0; b0 = d2; i0 = j; }
        else if (d2 < b1) { b2 = b1; i2 = i1; b1 = d2; i1 = j; }
        else if (d2 < b2) { b2 = d2; i2 = j; }
    }
    float w0 = 1.0f / fmaxf(b0, 1e-16f);
    float w1 = 1.0f / fmaxf(b1, 1e-16f);
    float w2 = 1.0f / fmaxf(b2, 1e-16f);
    float inv = 1.0f / (w0 + w1 + w2);
    size_t o = (size_t)tg * 3;
    kidx[o] = i0; kidx[o + 1] = i1; kidx[o + 2] = i2;
    kw[o] = w0 * inv; kw[o + 1] = w1 * inv; kw[o + 2] = w2 * inv;
}

// ---------------- K6b: interpolate + concat skip -> cat[f][256] -------------
__global__ __launch_bounds__(256) void interp_cat_kernel(
    const float* __restrict__ xc, const float* __restrict__ xs,
    const int* __restrict__ kidx, const float* __restrict__ kw,
    float* __restrict__ cat, int nf, int nc) {
    const int f = blockIdx.x;
    const int t = threadIdx.x;
    const int b = f / nf;
    const size_t o = (size_t)f * 3;
    if (t < 128) {
        int i0 = kidx[o], i1 = kidx[o + 1], i2 = kidx[o + 2];
        float w0 = kw[o], w1 = kw[o + 1], w2 = kw[o + 2];
        const float* X = xc + (size_t)b * nc * 128;
        float y = w0 * X[(size_t)i0 * 128 + t] + w1 * X[(size_t)i1 * 128 + t] +
                  w2 * X[(size_t)i2 * 128 + t];
        cat[(size_t)f * 256 + t] = y;
    } else {
        cat[(size_t)f * 256 + t] = xs[(size_t)f * 128 + (t - 128)];
    }
}

// ---------------- K7: generic GEMM + bias + relu + BN epilogue --------------
__global__ __launch_bounds__(256) void gemm_bn_kernel(
    const float* __restrict__ A, const float* __restrict__ W,
    const float* __restrict__ bias, const float* __restrict__ g,
    const float* __restrict__ be, float* __restrict__ C, int Kin, int Cout) {
    __shared__ __align__(16) float shA[64][33];
    __shared__ __align__(16) float shB[32][68];
    const int t = threadIdx.x;
    const int r0 = blockIdx.x * 64;
    const int c0 = blockIdx.y * 64;
    const int tr = t >> 4, tc = t & 15;
    const float invs = 1.0f / sqrtf(1.0f + EPSF);
    float acc[16];
#pragma unroll
    for (int i = 0; i < 16; ++i) acc[i] = 0.0f;
    for (int k0 = 0; k0 < Kin; k0 += 32) {
#pragma unroll
        for (int e = t; e < 2048; e += 256) {
            int r = e >> 5, kk = e & 31;
            shA[r][kk] = A[(size_t)(r0 + r) * Kin + k0 + kk];
        }
#pragma unroll
        for (int e = t; e < 2048; e += 256) {
            int kk = e >> 6, cc = e & 63;
            shB[kk][cc] = W[(size_t)(k0 + kk) * Cout + c0 + cc];
        }
        __syncthreads();
        for (int kk = 0; kk < 32; ++kk) {
            float av[4];
#pragma unroll
            for (int i = 0; i < 4; ++i) av[i] = shA[4 * tr + i][kk];
            const float4 wv = *(const float4*)&shB[kk][4 * tc];
            const float wa[4] = {wv.x, wv.y, wv.z, wv.w};
#pragma unroll
            for (int i = 0; i < 4; ++i)
#pragma unroll
                for (int jj = 0; jj < 4; ++jj)
                    acc[i * 4 + jj] = fmaf(av[i], wa[jj], acc[i * 4 + jj]);
        }
        __syncthreads();
    }
#pragma unroll
    for (int i = 0; i < 4; ++i)
#pragma unroll
        for (int jj = 0; jj < 4; ++jj) {
            int col = c0 + 4 * tc + jj;
            float z = fmaxf(acc[i * 4 + jj] + bias[col], 0.0f);
            C[(size_t)(r0 + 4 * tr + i) * Cout + col] = g[col] * z * invs + be[col];
        }
}

// ---------------- K8: final 128 -> 2 layer ----------------------------------
__global__ __launch_bounds__(256) void lo2_kernel(
    const float* __restrict__ in, const float* __restrict__ w,
    const float* __restrict__ b, const float* __restrict__ g,
    const float* __restrict__ be, float* __restrict__ out) {
    __shared__ float sw[256];
    const int t = threadIdx.x;
    sw[t] = w[t];
    __syncthreads();
    const int row = blockIdx.x * 256 + t;
    const float invs = 1.0f / sqrtf(1.0f + EPSF);
    float a0 = b[0], a1 = b[1];
    const float* R = in + (size_t)row * 128;
    for (int k = 0; k < 128; ++k) {
        float a = R[k];
        a0 = fmaf(a, sw[k * 2], a0);
        a1 = fmaf(a, sw[k * 2 + 1], a1);
    }
    a0 = fmaxf(a0, 0.0f);
    a1 = fmaxf(a1, 0.0f);
    out[(size_t)row * 2]     = g[0] * a0 * invs + be[0];
    out[(size_t)row * 2 + 1] = g[1] * a1 * invs + be[1];
}

// ---------------------------------------------------------------------------
extern "C" void kernel_launch(void* const* d_in, const int* in_sizes, int n_in,
                              void* d_out, int out_size, void* d_ws, size_t ws_size,
                              hipStream_t stream) {
    const float* x      = (const float*)d_in[0];
    const float* pos    = (const float*)d_in[1];
    const float* lin_w  = (const float*)d_in[3];
    const float* lin_b  = (const float*)d_in[4];
    const float* sa_w1  = (const float*)d_in[5];
    const float* sa_b1  = (const float*)d_in[6];
    const float* sa_g1  = (const float*)d_in[7];
    const float* sa_be1 = (const float*)d_in[8];
    const float* sa_w2  = (const float*)d_in[9];
    const float* sa_b2  = (const float*)d_in[10];
    const float* sa_g2  = (const float*)d_in[11];
    const float* sa_be2 = (const float*)d_in[12];
    const float* fp_w1  = (const float*)d_in[13];
    const float* fp_b1  = (const float*)d_in[14];
    const float* fp_g1  = (const float*)d_in[15];
    const float* fp_be1 = (const float*)d_in[16];
    const float* fp_w2  = (const float*)d_in[17];
    const float* fp_b2  = (const float*)d_in[18];
    const float* fp_g2  = (const float*)d_in[19];
    const float* fp_be2 = (const float*)d_in[20];
    const float* lo_w1  = (const float*)d_in[21];
    const float* lo_b1  = (const float*)d_in[22];
    const float* lo_g1  = (const float*)d_in[23];
    const float* lo_be1 = (const float*)d_in[24];
    const float* lo_w2  = (const float*)d_in[25];
    const float* lo_b2  = (const float*)d_in[26];
    const float* lo_g2  = (const float*)d_in[27];
    const float* lo_be2 = (const float*)d_in[28];

    float* ws = (float*)d_ws;
    size_t off = 0;
    auto alloc = [&](size_t n) { float* p = ws + off; off += n; return p; };
    float* xb    = alloc(4 * 4096 * 128);
    float* q1    = alloc(4 * 2048 * 3);
    float* q2    = alloc(4 * 1024 * 3);
    float* q3    = alloc(4 * 512 * 3);
    float* h1    = alloc(4 * 2048 * 128);
    float* h2    = alloc(4 * 1024 * 128);
    float* h3    = alloc(4 * 512 * 128);
    int2* pairs1 = (int2*)alloc(4 * 2048 * 64 * 2);
    int2* pairs2 = (int2*)alloc(4 * 1024 * 64 * 2);
    int2* pairs3 = (int2*)alloc(4 * 512 * 64 * 2);
    unsigned* ctrs = (unsigned*)alloc(64);   // [0],[16],[32] per level
    int* kidx    = (int*)alloc(4 * 4096 * 3);
    float* kw    = alloc(4 * 4096 * 3);
    float* cat   = alloc(4 * 4096 * 256);
    float* mbuf  = alloc(4 * 4096 * 256);
    float* xfA   = alloc(4 * 4096 * 128);
    float* xfB   = alloc(4 * 4096 * 128);
    if (ws_size < off * sizeof(float)) return;

    lin_in_kernel<<<16384, 128, 0, stream>>>(x, lin_w, lin_b, xb);

    // ---- SA level 0: 4096 -> 2048 (m=2048, lm=11, n=4096, ln=12) ----
    fps_kernel<4096, 512><<<4, 512, 0, stream>>>(pos, q1, 2048);
    zero_kernel<<<(4 * 2048 * 128 + 255) / 256, 256, 0, stream>>>(h1, 4 * 2048 * 128, ctrs + 0);
    nbr_kernel<64, 2><<<4096, 128, 0, stream>>>(pos, q1, pairs1, ctrs + 0, 4096, 2048);
    sa_fused_kernel<<<8192, 256, 0, stream>>>(xb, pos, q1, pairs1, ctrs + 0,
        sa_w1, sa_b1, sa_g1, sa_be1, sa_w2, sa_b2, sa_g2, sa_be2, h1, 11, 12);

    // ---- SA level 1: 2048 -> 1024 ----
    fps_kernel<2048, 256><<<4, 256, 0, stream>>>(q1, q2, 1024);
    zero_kernel<<<(4 * 1024 * 128 + 255) / 256, 256, 0, stream>>>(h2, 4 * 1024 * 128, ctrs + 16);
    nbr_kernel<32, 4><<<1024, 256, 0, stream>>>(q1, q2, pairs2, ctrs + 16, 2048, 1024);
    sa_fused_kernel<<<4096, 256, 0, stream>>>(h1, q1, q2, pairs2, ctrs + 16,
        sa_w1 + 131 * 131, sa_b1 + 131, sa_g1 + 131, sa_be1 + 131,
        sa_w2 + 131 * 128, sa_b2 + 128, sa_g2 + 128, sa_be2 + 128, h2, 10, 11);

    // ---- SA level 2: 1024 -> 512 ----
    fps_kernel<1024, 256><<<4, 256, 0, stream>>>(q2, q3, 512);
    zero_kernel<<<(4 * 512 * 128 + 255) / 256, 256, 0, stream>>>(h3, 4 * 512 * 128, ctrs + 32);
    nbr_kernel<16, 4><<<512, 256, 0, stream>>>(q2, q3, pairs3, ctrs + 32, 1024, 512);
    sa_fused_kernel<<<2048, 256, 0, stream>>>(h2, q2, q3, pairs3, ctrs + 32,
        sa_w1 + 2 * 131 * 131, sa_b1 + 2 * 131, sa_g1 + 2 * 131, sa_be1 + 2 * 131,
        sa_w2 + 2 * 131 * 128, sa_b2 + 2 * 128, sa_g2 + 2 * 128, sa_be2 + 2 * 128, h3, 9, 10);

    // ---- FP step 0 (mi=2): 512 -> 1024 ----
    knn_kernel<<<(4 * 1024) / 256, 256, 0, stream>>>(q2, q3, kidx, kw, 1024, 512);
    interp_cat_kernel<<<4 * 1024, 256, 0, stream>>>(h3, h2, kidx, kw, cat, 1024, 512);
    gemm_bn_kernel<<<dim3(4096 / 64, 4), 256, 0, stream>>>(cat,
        fp_w1 + 2 * 256 * 256, fp_b1 + 2 * 256, fp_g1 + 2 * 256, fp_be1 + 2 * 256,
        mbuf, 256, 256);
    gemm_bn_kernel<<<dim3(4096 / 64, 2), 256, 0, stream>>>(mbuf,
        fp_w2 + 2 * 256 * 128, fp_b2 + 2 * 128, fp_g2 + 2 * 128, fp_be2 + 2 * 128,
        xfA, 256, 128);

    // ---- FP step 1 (mi=1): 1024 -> 2048 ----
    knn_kernel<<<(4 * 2048) / 256, 256, 0, stream>>>(q1, q2, kidx, kw, 2048, 1024);
    interp_cat_kernel<<<4 * 2048, 256, 0, stream>>>(xfA, h1, kidx, kw, cat, 2048, 1024);
    gemm_bn_kernel<<<dim3(8192 / 64, 4), 256, 0, stream>>>(cat,
        fp_w1 + 256 * 256, fp_b1 + 256, fp_g1 + 256, fp_be1 + 256,
        mbuf, 256, 256);
    gemm_bn_kernel<<<dim3(8192 / 64, 2), 256, 0, stream>>>(mbuf,
        fp_w2 + 256 * 128, fp_b2 + 128, fp_g2 + 128, fp_be2 + 128,
        xfB, 256, 128);

    // ---- FP step 2 (mi=0): 2048 -> 4096 ----
    knn_kernel<<<(4 * 4096) / 256, 256, 0, stream>>>(pos, q1, kidx, kw, 4096, 2048);
    interp_cat_kernel<<<4 * 4096, 256, 0, stream>>>(xfB, xb, kidx, kw, cat, 4096, 2048);
    gemm_bn_kernel<<<dim3(16384 / 64, 4), 256, 0, stream>>>(cat,
        fp_w1, fp_b1, fp_g1, fp_be1, mbuf, 256, 256);
    gemm_bn_kernel<<<dim3(16384 / 64, 2), 256, 0, stream>>>(mbuf,
        fp_w2, fp_b2, fp_g2, fp_be2, xfA, 256, 128);

    // ---- output MLP ----
    gemm_bn_kernel<<<dim3(16384 / 64, 2), 256, 0, stream>>>(xfA,
        lo_w1, lo_b1, lo_g1, lo_be1, mbuf, 128, 128);
    lo2_kernel<<<16384 / 256, 256, 0, stream>>>(mbuf, lo_w2, lo_b2, lo_g2, lo_be2,
        (float*)d_out);
}